// Round 8
// baseline (1377.167 us; speedup 1.0000x reference)
//
#include <hip/hip_runtime.h>
#include <hip/hip_bf16.h>
#include <hip/hip_fp16.h>
#include <stdint.h>

// Problem constants (match reference)
#define NN   10000
#define GG   100
#define NPG  100
#define EE   400000
#define EPG  4000
#define CC   32
#define LM   16
#define SS   4
#define NBES 8
#define NLAYER 3
#define INV_AVG (1.0f/40.0f)
#define MAXDEG 128

typedef _Float16 f16x8 __attribute__((ext_vector_type(8)));
typedef _Float16 f16x4 __attribute__((ext_vector_type(4)));
typedef float    f32x4 __attribute__((ext_vector_type(4)));

__device__ __forceinline__ float siluf(float x) { return x / (1.0f + __expf(-x)); }
__device__ __forceinline__ int lof(int m) { return (m >= 1) + (m >= 4) + (m >= 9); }

// ---------------------------------------------------------------------------
// Kernel 1: per-edge geometry -> Y[E,16] f32, ef[E,8] f16  (layer-invariant)
// XCD-swizzled so Y/ef lines land in the XCD that will consume them.
// ---------------------------------------------------------------------------
__global__ __launch_bounds__(256) void k_geom(
    const float* __restrict__ pos, const float* __restrict__ cell,
    const int* __restrict__ Sij, const int* __restrict__ eidx,
    const int* __restrict__ batch, float* __restrict__ Y, __half* __restrict__ ef)
{
  int eb = (blockIdx.x & 7) * 196 + (blockIdx.x >> 3);
  if (eb >= 1563) return;
  int e = eb * 256 + threadIdx.x;
  if (e >= EE) return;
  int ia = eidx[e], ja = eidx[EE + e];
  int g = batch[ia];
  float s0 = (float)Sij[e*3+0], s1 = (float)Sij[e*3+1], s2 = (float)Sij[e*3+2];
  const float* cg = cell + g*9;
  float shx = s0*cg[0] + s1*cg[3] + s2*cg[6];
  float shy = s0*cg[1] + s1*cg[4] + s2*cg[7];
  float shz = s0*cg[2] + s1*cg[5] + s2*cg[8];
  float rx = (pos[ja*3+0] - pos[ia*3+0] + shx) / 6.0f;
  float ry = (pos[ja*3+1] - pos[ia*3+1] + shy) / 6.0f;
  float rz = (pos[ja*3+2] - pos[ia*3+2] + shz) / 6.0f;
  float r2 = rx*rx + ry*ry + rz*rz;
  float r  = sqrtf(r2);
  float rs = (r > 1e-9f) ? r : 1e-9f;
  float inv = 1.0f / rs;
  float x = rx*inv, y = ry*inv, z = rz*inv;

  const float s3   = 1.7320508075688772f;
  const float s15  = 3.872983346207417f;
  const float s5h  = 1.118033988749895f;
  const float s15h = 1.9364916731037085f;
  const float s358 = 2.091650066335189f;
  const float s105 = 10.246950765959598f;
  const float s218 = 1.620185174601965f;
  const float s7h  = 1.3228756555322954f;
  const float s105h= 5.123475382979799f;

  float xx = x*x, yy = y*y, zz = z*z;
  float yv[16];
  yv[0]  = 1.0f;
  yv[1]  = s3*x;  yv[2] = s3*y;  yv[3] = s3*z;
  yv[4]  = s15*x*y; yv[5] = s15*y*z; yv[6] = s5h*(3.0f*zz - 1.0f);
  yv[7]  = s15*x*z; yv[8] = s15h*(xx - yy);
  yv[9]  = s358*y*(3.0f*xx - yy);
  yv[10] = s105*x*y*z;
  yv[11] = s218*y*(5.0f*zz - 1.0f);
  yv[12] = s7h*(5.0f*zz*z - 3.0f*z);
  yv[13] = s218*x*(5.0f*zz - 1.0f);
  yv[14] = s105h*z*(xx - yy);
  yv[15] = s358*x*(xx - 3.0f*yy);

  float4* Yp = (float4*)(Y + (size_t)e*16);
  Yp[0] = make_float4(yv[0], yv[1], yv[2], yv[3]);
  Yp[1] = make_float4(yv[4], yv[5], yv[6], yv[7]);
  Yp[2] = make_float4(yv[8], yv[9], yv[10], yv[11]);
  Yp[3] = make_float4(yv[12], yv[13], yv[14], yv[15]);

  float f = 0.0f;
  if (r < 1.0f) f = 1.0f - 6.0f*r2 + 8.0f*r2*r - 3.0f*r2*r2;
  float c1 = 1.4142135623730951f * f * inv;
  float ang = 3.14159265358979323846f * rs;
  float sn = __sinf(ang), cn = __cosf(ang);
  float twoc = 2.0f * cn;
  float sprev = 0.0f, scur = sn;
  union { __half h[8]; uint4 u; } p;
  #pragma unroll
  for (int n1 = 1; n1 <= NBES; ++n1) {
    p.h[n1-1] = __float2half(c1 * scur);
    float snext = twoc * scur - sprev;
    sprev = scur; scur = snext;
  }
  *(uint4*)(ef + (size_t)e*8) = p.u;
}

// ---------------------------------------------------------------------------
// CSR build (layer-invariant)
// ---------------------------------------------------------------------------
__global__ __launch_bounds__(256) void k_csr_zero(int* __restrict__ cnt) {
  int n = blockIdx.x * 256 + threadIdx.x;
  if (n < NN) cnt[n] = 0;
}

__global__ __launch_bounds__(256) void k_csr_count(
    const int* __restrict__ eidx, int* __restrict__ cnt) {
  int e = blockIdx.x * 256 + threadIdx.x;
  if (e < EE) atomicAdd(&cnt[eidx[e]], 1);
}

__global__ __launch_bounds__(128) void k_csr_scan(
    const int* __restrict__ cnt, int* __restrict__ off, int* __restrict__ cursor) {
  __shared__ int s[128];
  int g = blockIdx.x, t = threadIdx.x;
  int own = (t < NPG) ? cnt[g*NPG + t] : 0;
  s[t] = own;
  __syncthreads();
  #pragma unroll
  for (int d = 1; d < 128; d <<= 1) {
    int v = (t >= d) ? s[t-d] : 0;
    __syncthreads();
    s[t] += v;
    __syncthreads();
  }
  if (t < NPG) {
    int o = g*EPG + s[t] - own;
    off[g*NPG + t] = o;
    cursor[g*NPG + t] = o;
    if (g == GG-1 && t == NPG-1) off[NN] = EE;
  }
}

__global__ __launch_bounds__(256) void k_csr_fill(
    const int* __restrict__ eidx, int* __restrict__ cursor, int2* __restrict__ elist) {
  int e = blockIdx.x * 256 + threadIdx.x;
  if (e >= EE) return;
  int ia = eidx[e], ja = eidx[EE + e];
  int pos = atomicAdd(&cursor[ia], 1);
  elist[pos] = make_int2(e, ja);
}

// ---------------------------------------------------------------------------
// Weight conversion (once per call): W2t[l][j][k], W3t[l][j][k] fp16
// ---------------------------------------------------------------------------
__global__ __launch_bounds__(256) void k_wconv(
    const float* __restrict__ W2, const float* __restrict__ W3,
    _Float16* __restrict__ W2t, _Float16* __restrict__ W3t)
{
  int idx = blockIdx.x * 256 + threadIdx.x;
  if (idx < NLAYER*64*64) {
    int l = idx / 4096, rem = idx % 4096, k = rem / 64, j = rem % 64;
    W2t[l*4096 + j*64 + k] = (_Float16)W2[idx];
  }
  if (idx < NLAYER*64*256) {
    int l = idx / 16384, rem = idx % 16384, k = rem / 256, j = rem % 256;
    W3t[l*16384 + j*64 + k] = (_Float16)W3[idx];
  }
}

// ---------------------------------------------------------------------------
// Kernel 2: node init
// ---------------------------------------------------------------------------
__global__ __launch_bounds__(256) void k_init(
    const int* __restrict__ species, const float* __restrict__ W_emb,
    const float* __restrict__ W_xtp, float* __restrict__ h,
    float* __restrict__ xnode, float* __restrict__ node_e)
{
  int idx = blockIdx.x * 256 + threadIdx.x;
  if (idx >= NN*CC) return;
  int n = idx / CC, c = idx % CC;
  int sp = species[n];
  float h0 = W_emb[sp*CC + c];
  float* hp = h + (size_t)n*512 + c*16;
  hp[0] = h0;
  #pragma unroll
  for (int m = 1; m < 16; ++m) hp[m] = 0.0f;
  if (c == 0) {
    float xn = 0.0f;
    for (int c2 = 0; c2 < CC; ++c2) xn += W_emb[sp*CC + c2] * W_xtp[c2*SS + sp];
    xnode[n] = xn;
    node_e[n] = 0.0f;
  }
}

// ---------------------------------------------------------------------------
// Kernel 3 (layer 0 only): hu = h @ Wu, coalesced weight access
// ---------------------------------------------------------------------------
__global__ __launch_bounds__(256) void k_hu(
    const float* __restrict__ h, const float* __restrict__ Wu,
    float* __restrict__ hu)
{
  __shared__ float h_s[512];
  __shared__ float hu_s[512];
  int n = blockIdx.x, t = threadIdx.x;
  h_s[t]       = h[(size_t)n*512 + t];
  h_s[t + 256] = h[(size_t)n*512 + t + 256];
  __syncthreads();
  int lane = t & 63, wv = t >> 6;
  int d = lane & 31, ch = lane >> 5;
  #pragma unroll
  for (int mi = 0; mi < 4; ++mi) {
    int m = wv*4 + mi;
    int l = lof(m);
    const float* wu = Wu + l*1024 + d;
    float u = 0.0f;
    #pragma unroll 4
    for (int cc = 0; cc < 16; ++cc) {
      int c = cc + ch*16;
      u += h_s[c*16 + m] * wu[c*32];
    }
    u += __shfl_xor(u, 32);
    if (ch == 0) hu_s[d*16 + m] = u;
  }
  __syncthreads();
  hu[(size_t)n*512 + t]       = hu_s[t];
  hu[(size_t)n*512 + t + 256] = hu_s[t + 256];
}

// ---------------------------------------------------------------------------
// Kernel 4 (per layer): edge MLP, edge-major streaming:
// ef(8) -> hm1(64) fp32 VALU -> hm2(64) MFMA, silu, fp16 global.
// 64 edges/block (16/wave), wave-autonomous, XCD-swizzled to match gather.
// ---------------------------------------------------------------------------
__global__ __launch_bounds__(256) void k_mlp(
    const __half* __restrict__ ef, const float* __restrict__ W1,
    const float* __restrict__ b1, const _Float16* __restrict__ W2t,
    const float* __restrict__ b2, __half* __restrict__ hm2)
{
  __shared__ _Float16 hm1_s[4][16*72];
  int b = blockIdx.x, t = threadIdx.x;
  int eb = (b & 7) * 782 + (b >> 3);
  if (eb >= EE/64) return;
  int wv = t >> 6, lane = t & 63;
  int ln15 = lane & 15, quad = lane >> 4;
  _Float16* hm1 = hm1_s[wv];
  size_t e16 = (size_t)eb*64 + wv*16;

  // GEMM1: edge e16+ln15, all 64 cols (lane covers 4 cols x 4 passes)
  union { uint4 u; __half hh[8]; } efv;
  efv.u = *(const uint4*)(ef + (e16 + ln15)*8);
  float ev[8];
  #pragma unroll
  for (int k = 0; k < 8; ++k) ev[k] = __half2float(efv.hh[k]);
  #pragma unroll
  for (int p = 0; p < 4; ++p) {
    int j0 = p*16 + quad*4;
    float4 a = *(const float4*)(b1 + j0);
    #pragma unroll
    for (int k = 0; k < 8; ++k) {
      const float4 w = *(const float4*)(W1 + k*64 + j0);
      a.x += ev[k]*w.x; a.y += ev[k]*w.y; a.z += ev[k]*w.z; a.w += ev[k]*w.w;
    }
    f16x4 pk;
    pk[0] = (_Float16)siluf(a.x);
    pk[1] = (_Float16)siluf(a.y);
    pk[2] = (_Float16)siluf(a.z);
    pk[3] = (_Float16)siluf(a.w);
    *(f16x4*)&hm1[ln15*72 + j0] = pk;
  }

  // GEMM2: MFMA, 4 col-groups
  f16x8 a0 = *(const f16x8*)(hm1 + ln15*72 + quad*8);
  f16x8 a1 = *(const f16x8*)(hm1 + ln15*72 + 32 + quad*8);
  #pragma unroll
  for (int cg = 0; cg < 4; ++cg) {
    int col = cg*16 + ln15;
    f32x4 d = {0.f, 0.f, 0.f, 0.f};
    d = __builtin_amdgcn_mfma_f32_16x16x32_f16(a0, *(const f16x8*)(W2t + (size_t)col*64 + quad*8), d, 0, 0, 0);
    d = __builtin_amdgcn_mfma_f32_16x16x32_f16(a1, *(const f16x8*)(W2t + (size_t)col*64 + 32 + quad*8), d, 0, 0, 0);
    float bb = b2[col];
    #pragma unroll
    for (int r = 0; r < 4; ++r)
      hm2[(e16 + quad*4 + r)*64 + col] = __float2half(siluf(d[r] + bb));
  }
}

// ---------------------------------------------------------------------------
// Kernel 5 (per layer): WAVE-PER-NODE fused gather + update + readout + hu.
// Zero __syncthreads: each wave owns one node; GEMM3 A-frags straight from
// global hm2; rw in a private fp16 LDS slab; epilogue in [m*32+c] layouts.
// ---------------------------------------------------------------------------
__global__ __launch_bounds__(256) void k_gather(
    const int2* __restrict__ elist, const int* __restrict__ off,
    const float* __restrict__ Y, const __half* __restrict__ hm2,
    const _Float16* __restrict__ W3t, const float* __restrict__ hu_in,
    const int* __restrict__ species, const float* __restrict__ xnode,
    const float* __restrict__ Wd, const float* __restrict__ Wsc,
    const float* __restrict__ Wr1, const float* __restrict__ br1,
    const float* __restrict__ Wr2, float* __restrict__ node_e,
    const float* __restrict__ Wu_next, float* __restrict__ hu_out,
    float* __restrict__ h, int has_next)
{
  // per-wave slab: tile phase rw[16][264] fp16 (8448 B); epilogue phase
  // al[m*32+c] / h[c*16+m] / out[m*32+c] / hu[m*32+c] (4x2048 B = 8192 B)
  __shared__ _Float16 slab_s[4][4224];
  __shared__ int2 elw_s[4][MAXDEG];

  int b = blockIdx.x, t = threadIdx.x;
  int lb = (b & 7) * 313 + (b >> 3);   // XCD swizzle: 8 x 313 >= 2500
  if (lb >= NN/4) return;
  int wv = t >> 6, lane = t & 63;
  int ln15 = lane & 15, quad = lane >> 4;
  int n = lb*4 + wv;

  _Float16* rw = slab_s[wv];
  float* fs = (float*)slab_s[wv];
  int2* elw = elw_s[wv];
  const _Float16* hm2h = (const _Float16*)hm2;

  int beg = off[n];
  int deg = off[n+1] - beg;
  if (deg > MAXDEG) deg = MAXDEG;
  for (int i = lane; i < deg; i += 64) elw[i] = elist[beg + i];

  int c = lane >> 1, half = lane & 1, mb = half * 8;
  float acc[8] = {0.f,0.f,0.f,0.f,0.f,0.f,0.f,0.f};

  for (int base = 0; base < deg; base += 16) {
    int cnt = min(16, deg - base);
    int ia = base + ln15; if (ia >= deg) ia = deg - 1;
    int ea = elw[ia].x;
    f16x8 a0 = *(const f16x8*)(hm2h + (size_t)ea*64 + quad*8);
    f16x8 a1 = *(const f16x8*)(hm2h + (size_t)ea*64 + 32 + quad*8);
    #pragma unroll
    for (int cg = 0; cg < 16; ++cg) {
      int col = cg*16 + ln15;
      f32x4 d = {0.f, 0.f, 0.f, 0.f};
      d = __builtin_amdgcn_mfma_f32_16x16x32_f16(a0, *(const f16x8*)(W3t + (size_t)col*64 + quad*8), d, 0, 0, 0);
      d = __builtin_amdgcn_mfma_f32_16x16x32_f16(a1, *(const f16x8*)(W3t + (size_t)col*64 + 32 + quad*8), d, 0, 0, 0);
      #pragma unroll
      for (int r = 0; r < 4; ++r)
        rw[(quad*4 + r)*264 + col] = (_Float16)d[r];
    }
    // message accumulate (wave-local; compiler inserts lgkmcnt waits)
    #pragma unroll 2
    for (int i = 0; i < cnt; ++i) {
      int2 ed = elw[base + i];
      const float* hup = hu_in + (size_t)ed.y*512 + c*16;
      float hj0 = hup[0];
      float4 hA = *(const float4*)(hup + mb);
      float4 hB = *(const float4*)(hup + mb + 4);
      const float* Yp = Y + (size_t)ed.x*16 + mb;
      float4 yA = *(const float4*)(Yp);
      float4 yB = *(const float4*)(Yp + 4);
      f16x4 w0v = *(const f16x4*)&rw[i*264 + c*4];
      f16x4 w1v = *(const f16x4*)&rw[i*264 + 128 + c*4];
      float u00 = (float)w0v[0], u01 = (float)w0v[1], u02 = (float)w0v[2], u03 = (float)w0v[3];
      float u10 = (float)w1v[0], u11 = (float)w1v[1], u12 = (float)w1v[2], u13 = (float)w1v[3];
      // l(m) pattern: half0 -> {0,1,1,1,2,2,2,2}; half1 -> {2,3,3,3,3,3,3,3}
      float s0a = half ? u02 : u00, s0b = half ? u03 : u01, s0c = half ? u03 : u02;
      float s1a = half ? u12 : u10, s1b = half ? u13 : u11, s1c = half ? u13 : u12;
      acc[0] += s0a*(yA.x*hj0) + s1a*hA.x;
      acc[1] += s0b*(yA.y*hj0) + s1b*hA.y;
      acc[2] += s0b*(yA.z*hj0) + s1b*hA.z;
      acc[3] += s0b*(yA.w*hj0) + s1b*hA.w;
      acc[4] += s0c*(yB.x*hj0) + s1c*hB.x;
      acc[5] += s0c*(yB.y*hj0) + s1c*hB.y;
      acc[6] += s0c*(yB.z*hj0) + s1c*hB.z;
      acc[7] += s0c*(yB.w*hj0) + s1c*hB.w;
    }
  }

  // ---- epilogue (wave-private) ----
  #pragma unroll
  for (int j = 0; j < 8; ++j) fs[(mb + j)*32 + c] = acc[j] * INV_AVG;
  {
    const float* hg = h + (size_t)n*512 + lane*8;
    *(float4*)&fs[512 + lane*8]     = *(const float4*)(hg);
    *(float4*)&fs[512 + lane*8 + 4] = *(const float4*)(hg + 4);
  }
  int sp = species[n];
  float xn = xnode[n];
  int d = lane & 31, ch = lane >> 5;
  #pragma unroll
  for (int m = 0; m < 16; ++m) {
    const int l = lof(m);
    const float* wd  = Wd  + l*1024 + d;
    const float* wsc = Wsc + l*4096 + sp*32 + d;
    float a = 0.f, s = 0.f;
    #pragma unroll 4
    for (int cc = 0; cc < 16; ++cc) {
      int c2 = cc + ch*16;
      a += fs[m*32 + c2]       * wd[c2*32];
      s += fs[512 + c2*16 + m] * wsc[c2*128];
    }
    a += __shfl_xor(a, 32);
    s += __shfl_xor(s, 32);
    if (ch == 0) fs[1024 + m*32 + d] = a*xn + s;
  }
  if (has_next) {
    #pragma unroll
    for (int m = 0; m < 16; ++m) {
      const int l = lof(m);
      const float* wu = Wu_next + l*1024 + d;
      float u = 0.f;
      #pragma unroll 4
      for (int cc = 0; cc < 16; ++cc) {
        int c2 = cc + ch*16;
        u += fs[1024 + m*32 + c2] * wu[c2*32];
      }
      u += __shfl_xor(u, 32);
      if (ch == 0) fs[1536 + m*32 + d] = u;
    }
  }
  // readout: node_e += silu( silu(h_new[:,0] @ Wr1 + br1) @ Wr2 )
  {
    float pre = br1[lane];
    #pragma unroll 4
    for (int cc = 0; cc < CC; ++cc) pre += fs[1024 + cc] * Wr1[cc*64 + lane];
    float v = siluf(pre) * Wr2[lane];
    #pragma unroll
    for (int o = 32; o > 0; o >>= 1) v += __shfl_down(v, o);
    if (lane == 0) node_e[n] += siluf(v);
  }
  // coalesced writebacks (convert [m*32+c] -> [c*16+m])
  {
    float* hg = h + (size_t)n*512;
    float vo[8];
    #pragma unroll
    for (int q = 0; q < 8; ++q) {
      int L = lane*8 + q;
      vo[q] = fs[1024 + (L & 15)*32 + (L >> 4)];
    }
    *(float4*)(hg + lane*8)     = make_float4(vo[0], vo[1], vo[2], vo[3]);
    *(float4*)(hg + lane*8 + 4) = make_float4(vo[4], vo[5], vo[6], vo[7]);
    if (has_next) {
      float* ug = hu_out + (size_t)n*512;
      float vu[8];
      #pragma unroll
      for (int q = 0; q < 8; ++q) {
        int L = lane*8 + q;
        vu[q] = fs[1536 + (L & 15)*32 + (L >> 4)];
      }
      *(float4*)(ug + lane*8)     = make_float4(vu[0], vu[1], vu[2], vu[3]);
      *(float4*)(ug + lane*8 + 4) = make_float4(vu[4], vu[5], vu[6], vu[7]);
    }
  }
}

// ---------------------------------------------------------------------------
// Kernel 7: per-graph sum of node energies
// ---------------------------------------------------------------------------
__global__ __launch_bounds__(128) void k_out(
    const float* __restrict__ node_e, float* __restrict__ out)
{
  int g = blockIdx.x, t = threadIdx.x;
  float v = (t < NPG) ? node_e[g*NPG + t] : 0.0f;
  #pragma unroll
  for (int off2 = 32; off2 > 0; off2 >>= 1) v += __shfl_down(v, off2);
  __shared__ float r2[2];
  if ((t & 63) == 0) r2[t >> 6] = v;
  __syncthreads();
  if (t == 0) out[g] = r2[0] + r2[1];
}

// Diagnostic: if workspace too small, report its size (MB) via absmax
__global__ void k_dbg(float* __restrict__ out, float v) {
  int i = blockIdx.x * 64 + threadIdx.x;
  if (i < GG) out[i] = v;
}

// ---------------------------------------------------------------------------
extern "C" void kernel_launch(void* const* d_in, const int* in_sizes, int n_in,
                              void* d_out, int out_size, void* d_ws, size_t ws_size,
                              hipStream_t stream)
{
  const float* positions = (const float*)d_in[0];
  const float* cell      = (const float*)d_in[1];
  const int*   Sij       = (const int*)d_in[2];
  const int*   eidx      = (const int*)d_in[3];
  const int*   species   = (const int*)d_in[4];
  const int*   batch     = (const int*)d_in[5];
  const float* W_emb     = (const float*)d_in[6];
  const float* W_xtp     = (const float*)d_in[7];
  const float* W_up      = (const float*)d_in[8];
  const float* W1        = (const float*)d_in[9];
  const float* b1        = (const float*)d_in[10];
  const float* W2        = (const float*)d_in[11];
  const float* b2        = (const float*)d_in[12];
  const float* W3        = (const float*)d_in[13];
  const float* W_down    = (const float*)d_in[14];
  const float* W_sc      = (const float*)d_in[15];
  const float* Wr1       = (const float*)d_in[16];
  const float* br1       = (const float*)d_in[17];
  const float* Wr2       = (const float*)d_in[18];
  float* out = (float*)d_out;
  (void)in_sizes; (void)n_in; (void)out_size;

  const size_t NEED = 149000000;  // ~148.2 MB actual (ws proven >= 152 MB in R2)
  if (ws_size < NEED) {
    k_dbg<<<dim3(2), dim3(64), 0, stream>>>(out, (float)(ws_size >> 20));
    return;
  }

  char* ws = (char*)d_ws;
  size_t off = 0;
  auto alloc = [&](size_t bytes) -> void* {
    void* p = ws + off;
    off += (bytes + 255) & ~(size_t)255;
    return p;
  };
  float*     Yb      = (float*)alloc((size_t)EE*16*4);   // 25.6 MB
  __half*    efb     = (__half*)alloc((size_t)EE*8*2);   //  6.4 MB
  float*     hb      = (float*)alloc((size_t)NN*512*4);  // 20.5 MB
  float*     huA     = (float*)alloc((size_t)NN*512*4);  // 20.5 MB
  float*     huB     = (float*)alloc((size_t)NN*512*4);  // 20.5 MB
  float*     xnodeb  = (float*)alloc((size_t)NN*4);
  float*     node_eb = (float*)alloc((size_t)NN*4);
  int*       offb    = (int*)alloc((size_t)(NN+1)*4);
  int*       curb    = (int*)alloc((size_t)NN*4);
  int2*      elistb  = (int2*)alloc((size_t)EE*8);       //  3.2 MB
  _Float16*  W2tb    = (_Float16*)alloc((size_t)NLAYER*64*64*2);
  _Float16*  W3tb    = (_Float16*)alloc((size_t)NLAYER*64*256*2);
  __half*    hm2b    = (__half*)alloc((size_t)EE*64*2);  // 51.2 MB

  dim3 blk(256);
  k_geom<<<dim3(1568), blk, 0, stream>>>(positions, cell, Sij, eidx, batch, Yb, efb);
  k_init<<<dim3((NN*CC + 255)/256), blk, 0, stream>>>(species, W_emb, W_xtp, hb, xnodeb, node_eb);
  k_wconv<<<dim3((NLAYER*64*256 + 255)/256), blk, 0, stream>>>(W2, W3, W2tb, W3tb);

  // CSR build (layer-invariant)
  k_csr_zero <<<dim3((NN + 255)/256), blk, 0, stream>>>(curb);
  k_csr_count<<<dim3((EE + 255)/256), blk, 0, stream>>>(eidx, curb);
  k_csr_scan <<<dim3(GG), dim3(128), 0, stream>>>(curb, offb, curb);
  k_csr_fill <<<dim3((EE + 255)/256), blk, 0, stream>>>(eidx, curb, elistb);

  // layer 0 hu from initial h
  k_hu<<<dim3(NN), blk, 0, stream>>>(hb, W_up + 0*4096, huA);

  float* hin = huA; float* hout = huB;
  for (int layer = 0; layer < NLAYER; ++layer) {
    int has_next = (layer + 1 < NLAYER) ? 1 : 0;
    k_mlp<<<dim3(6256), blk, 0, stream>>>(efb,
        W1 + layer*NBES*64, b1 + layer*64,
        W2tb + layer*4096, b2 + layer*64, hm2b);
    k_gather<<<dim3(2504), blk, 0, stream>>>(elistb, offb, Yb, hm2b,
        W3tb + layer*16384, hin,
        species, xnodeb,
        W_down + layer*4096, W_sc + layer*16384,
        Wr1 + layer*CC*64, br1 + layer*64, Wr2 + layer*64, node_eb,
        W_up + (has_next ? (layer+1)*4096 : 0), hout, hb, has_next);
    float* tmp = hin; hin = hout; hout = tmp;
  }
  k_out<<<dim3(GG), dim3(128), 0, stream>>>(node_eb, out);
}

// Round 9
// 1095.729 us; speedup vs baseline: 1.2568x; 1.2568x over previous
//
#include <hip/hip_runtime.h>
#include <hip/hip_bf16.h>
#include <hip/hip_fp16.h>
#include <stdint.h>

// Problem constants (match reference)
#define NN   10000
#define GG   100
#define NPG  100
#define EE   400000
#define EPG  4000
#define CC   32
#define LM   16
#define SS   4
#define NBES 8
#define NLAYER 3
#define INV_AVG (1.0f/40.0f)

typedef _Float16 f16x8 __attribute__((ext_vector_type(8)));
typedef _Float16 f16x4 __attribute__((ext_vector_type(4)));
typedef float    f32x4 __attribute__((ext_vector_type(4)));

__device__ __forceinline__ float siluf(float x) { return x / (1.0f + __expf(-x)); }
__device__ __forceinline__ int lof(int m) { return (m >= 1) + (m >= 4) + (m >= 9); }

// ---------------------------------------------------------------------------
// Kernel 1: per-edge geometry -> Y[E,16] f32, ef[E,8] f16  (layer-invariant)
// ---------------------------------------------------------------------------
__global__ __launch_bounds__(256) void k_geom(
    const float* __restrict__ pos, const float* __restrict__ cell,
    const int* __restrict__ Sij, const int* __restrict__ eidx,
    const int* __restrict__ batch, float* __restrict__ Y, __half* __restrict__ ef)
{
  int e = blockIdx.x * 256 + threadIdx.x;
  if (e >= EE) return;
  int ia = eidx[e], ja = eidx[EE + e];
  int g = batch[ia];
  float s0 = (float)Sij[e*3+0], s1 = (float)Sij[e*3+1], s2 = (float)Sij[e*3+2];
  const float* cg = cell + g*9;
  float shx = s0*cg[0] + s1*cg[3] + s2*cg[6];
  float shy = s0*cg[1] + s1*cg[4] + s2*cg[7];
  float shz = s0*cg[2] + s1*cg[5] + s2*cg[8];
  float rx = (pos[ja*3+0] - pos[ia*3+0] + shx) / 6.0f;
  float ry = (pos[ja*3+1] - pos[ia*3+1] + shy) / 6.0f;
  float rz = (pos[ja*3+2] - pos[ia*3+2] + shz) / 6.0f;
  float r2 = rx*rx + ry*ry + rz*rz;
  float r  = sqrtf(r2);
  float rs = (r > 1e-9f) ? r : 1e-9f;
  float inv = 1.0f / rs;
  float x = rx*inv, y = ry*inv, z = rz*inv;

  const float s3   = 1.7320508075688772f;
  const float s15  = 3.872983346207417f;
  const float s5h  = 1.118033988749895f;
  const float s15h = 1.9364916731037085f;
  const float s358 = 2.091650066335189f;
  const float s105 = 10.246950765959598f;
  const float s218 = 1.620185174601965f;
  const float s7h  = 1.3228756555322954f;
  const float s105h= 5.123475382979799f;

  float xx = x*x, yy = y*y, zz = z*z;
  float yv[16];
  yv[0]  = 1.0f;
  yv[1]  = s3*x;  yv[2] = s3*y;  yv[3] = s3*z;
  yv[4]  = s15*x*y; yv[5] = s15*y*z; yv[6] = s5h*(3.0f*zz - 1.0f);
  yv[7]  = s15*x*z; yv[8] = s15h*(xx - yy);
  yv[9]  = s358*y*(3.0f*xx - yy);
  yv[10] = s105*x*y*z;
  yv[11] = s218*y*(5.0f*zz - 1.0f);
  yv[12] = s7h*(5.0f*zz*z - 3.0f*z);
  yv[13] = s218*x*(5.0f*zz - 1.0f);
  yv[14] = s105h*z*(xx - yy);
  yv[15] = s358*x*(xx - 3.0f*yy);

  float4* Yp = (float4*)(Y + (size_t)e*16);
  Yp[0] = make_float4(yv[0], yv[1], yv[2], yv[3]);
  Yp[1] = make_float4(yv[4], yv[5], yv[6], yv[7]);
  Yp[2] = make_float4(yv[8], yv[9], yv[10], yv[11]);
  Yp[3] = make_float4(yv[12], yv[13], yv[14], yv[15]);

  float f = 0.0f;
  if (r < 1.0f) f = 1.0f - 6.0f*r2 + 8.0f*r2*r - 3.0f*r2*r2;
  float c1 = 1.4142135623730951f * f * inv;
  float ang = 3.14159265358979323846f * rs;
  float sn = __sinf(ang), cn = __cosf(ang);
  float twoc = 2.0f * cn;
  float sprev = 0.0f, scur = sn;
  union { __half h[8]; uint4 u; } p;
  #pragma unroll
  for (int n1 = 1; n1 <= NBES; ++n1) {
    p.h[n1-1] = __float2half(c1 * scur);
    float snext = twoc * scur - sprev;
    sprev = scur; scur = snext;
  }
  *(uint4*)(ef + (size_t)e*8) = p.u;
}

// ---------------------------------------------------------------------------
// CSR build (layer-invariant)
// ---------------------------------------------------------------------------
__global__ __launch_bounds__(256) void k_csr_zero(int* __restrict__ cnt) {
  int n = blockIdx.x * 256 + threadIdx.x;
  if (n < NN) cnt[n] = 0;
}

__global__ __launch_bounds__(256) void k_csr_count(
    const int* __restrict__ eidx, int* __restrict__ cnt) {
  int e = blockIdx.x * 256 + threadIdx.x;
  if (e < EE) atomicAdd(&cnt[eidx[e]], 1);
}

__global__ __launch_bounds__(128) void k_csr_scan(
    const int* __restrict__ cnt, int* __restrict__ off, int* __restrict__ cursor) {
  __shared__ int s[128];
  int g = blockIdx.x, t = threadIdx.x;
  int own = (t < NPG) ? cnt[g*NPG + t] : 0;
  s[t] = own;
  __syncthreads();
  #pragma unroll
  for (int d = 1; d < 128; d <<= 1) {
    int v = (t >= d) ? s[t-d] : 0;
    __syncthreads();
    s[t] += v;
    __syncthreads();
  }
  if (t < NPG) {
    int o = g*EPG + s[t] - own;
    off[g*NPG + t] = o;
    cursor[g*NPG + t] = o;
    if (g == GG-1 && t == NPG-1) off[NN] = EE;
  }
}

__global__ __launch_bounds__(256) void k_csr_fill(
    const int* __restrict__ eidx, int* __restrict__ cursor, int2* __restrict__ elist) {
  int e = blockIdx.x * 256 + threadIdx.x;
  if (e >= EE) return;
  int ia = eidx[e], ja = eidx[EE + e];
  int pos = atomicAdd(&cursor[ia], 1);
  elist[pos] = make_int2(e, ja);
}

// ---------------------------------------------------------------------------
// Weight conversion (once per call): W2t[l][j][k], W3t[l][j][k] fp16
// ---------------------------------------------------------------------------
__global__ __launch_bounds__(256) void k_wconv(
    const float* __restrict__ W2, const float* __restrict__ W3,
    _Float16* __restrict__ W2t, _Float16* __restrict__ W3t)
{
  int idx = blockIdx.x * 256 + threadIdx.x;
  if (idx < NLAYER*64*64) {
    int l = idx / 4096, rem = idx % 4096, k = rem / 64, j = rem % 64;
    W2t[l*4096 + j*64 + k] = (_Float16)W2[idx];
  }
  if (idx < NLAYER*64*256) {
    int l = idx / 16384, rem = idx % 16384, k = rem / 256, j = rem % 256;
    W3t[l*16384 + j*64 + k] = (_Float16)W3[idx];
  }
}

// ---------------------------------------------------------------------------
// Kernel 2: node init
// ---------------------------------------------------------------------------
__global__ __launch_bounds__(256) void k_init(
    const int* __restrict__ species, const float* __restrict__ W_emb,
    const float* __restrict__ W_xtp, float* __restrict__ h,
    float* __restrict__ xnode, float* __restrict__ node_e)
{
  int idx = blockIdx.x * 256 + threadIdx.x;
  if (idx >= NN*CC) return;
  int n = idx / CC, c = idx % CC;
  int sp = species[n];
  float h0 = W_emb[sp*CC + c];
  float* hp = h + (size_t)n*512 + c*16;
  hp[0] = h0;
  #pragma unroll
  for (int m = 1; m < 16; ++m) hp[m] = 0.0f;
  if (c == 0) {
    float xn = 0.0f;
    for (int c2 = 0; c2 < CC; ++c2) xn += W_emb[sp*CC + c2] * W_xtp[c2*SS + sp];
    xnode[n] = xn;
    node_e[n] = 0.0f;
  }
}

// ---------------------------------------------------------------------------
// Kernel 3 (layer 0 only): hu = h @ Wu, coalesced weight access
// ---------------------------------------------------------------------------
__global__ __launch_bounds__(256) void k_hu(
    const float* __restrict__ h, const float* __restrict__ Wu,
    float* __restrict__ hu)
{
  __shared__ float h_s[512];
  __shared__ float hu_s[512];
  int n = blockIdx.x, t = threadIdx.x;
  h_s[t]       = h[(size_t)n*512 + t];
  h_s[t + 256] = h[(size_t)n*512 + t + 256];
  __syncthreads();
  int lane = t & 63, wv = t >> 6;
  int d = lane & 31, ch = lane >> 5;
  #pragma unroll
  for (int mi = 0; mi < 4; ++mi) {
    int m = wv*4 + mi;
    int l = lof(m);
    const float* wu = Wu + l*1024 + d;
    float u = 0.0f;
    #pragma unroll 4
    for (int cc = 0; cc < 16; ++cc) {
      int c = cc + ch*16;
      u += h_s[c*16 + m] * wu[c*32];
    }
    u += __shfl_xor(u, 32);
    if (ch == 0) hu_s[d*16 + m] = u;
  }
  __syncthreads();
  hu[(size_t)n*512 + t]       = hu_s[t];
  hu[(size_t)n*512 + t + 256] = hu_s[t + 256];
}

// ---------------------------------------------------------------------------
// Kernel 5 (per layer): fused per-node layer (R7 structure), with:
//  - fp16 rw slab + phase-overlaid epilogue LDS  => 13.8 KB total LDS
//  - cross-tile ef/elist prefetch (regs + shfl broadcast)
// Phases: [GEMM1 | B1 | GEMM2 | B2 | GEMM3 + prefetch + message] per tile;
// then B, al/h -> LDS (overlaying hm1/hm2), B, epilogue, B, writeback.
// ---------------------------------------------------------------------------
__global__ __launch_bounds__(256) void k_gather(
    const int2* __restrict__ elist, const int* __restrict__ off,
    const float* __restrict__ Y, const __half* __restrict__ ef,
    const float* __restrict__ W1, const float* __restrict__ b1,
    const _Float16* __restrict__ W2t, const float* __restrict__ b2,
    const _Float16* __restrict__ W3t, const float* __restrict__ hu_in,
    const int* __restrict__ species, const float* __restrict__ xnode,
    const float* __restrict__ Wd, const float* __restrict__ Wsc,
    const float* __restrict__ Wr1, const float* __restrict__ br1,
    const float* __restrict__ Wr2, float* __restrict__ node_e,
    const float* __restrict__ Wu_next, float* __restrict__ hu_out,
    float* __restrict__ h, int has_next)
{
  // 13824 B pool:
  //  phase1: hm1 f16[16][72] @0, hm2 f16[16][72] @2304, elw int2[4][16] @4608,
  //          rw f16[4][16][68] @5120
  //  phase2: al f32[512] @0, h2/out f32[512] @2048 (overlay; barrier-guarded)
  __shared__ float pool[3456];
  _Float16* hm1 = (_Float16*)pool;
  _Float16* hm2 = ((_Float16*)pool) + 16*72;
  int2* elw_all = (int2*)(pool + 1152);
  _Float16* rw_all = (_Float16*)(pool + 1280);
  float* al_s = pool;
  float* h2_s = pool + 512;

  int b = blockIdx.x, t = threadIdx.x;
  int n = (b & 7) * (NN/8) + (b >> 3);   // XCD-locality swizzle (NN = 8*1250)
  int beg = off[n], deg = off[n+1] - beg;

  int lane = t & 63, wv = t >> 6;
  int ln15 = lane & 15, quad = lane >> 4;
  _Float16* rww = rw_all + wv*(16*68);
  int2* elw = elw_all + wv*16;

  // stage this node's h in registers (LDS is busy until the epilogue)
  float hreg0 = h[(size_t)n*512 + t];
  float hreg1 = h[(size_t)n*512 + t + 256];

  // message mapping (wave-local: c in [wv*8, wv*8+8))
  int cl = lane >> 3, m0 = (lane & 7) * 2;
  int c = wv*8 + cl, cl4 = cl*4;
  int l0 = lof(m0), l1 = lof(m0 + 1);
  float acc0 = 0.0f, acc1 = 0.0f;

  // GEMM1: wave computes cols j1..j1+3 (j1 = wv*16 + quad*4) for edge ln15
  int j1 = wv*16 + quad*4;
  float4 b1v = *(const float4*)(b1 + j1);
  float  b2v = b2[wv*16 + ln15];

  // ---- prefetch tile 0 (elist in regs, ef via shfl-broadcast edge id)
  int2 eln_cur = make_int2(0, 0);
  uint4 efq_cur = make_uint4(0,0,0,0);
  if (deg > 0) {
    int idx = lane;  // lanes 0..15 meaningful
    int cidx = idx < deg ? idx : deg - 1;
    if (lane < 16) eln_cur = elist[beg + cidx];
    int e1 = __shfl(eln_cur.x, ln15);
    efq_cur = *(const uint4*)(ef + (size_t)e1*8);
  }

  for (int base = 0; base < deg; base += 16) {
    int cnt = min(16, deg - base);
    if (lane < 16) elw[lane] = eln_cur;   // publish edge list for message loop

    // ---- GEMM1: ef(8) -> hm1(64), fp32 VALU, silu, fp16 out (cooperative)
    {
      union { uint4 u; __half hh[8]; } efv; efv.u = efq_cur;
      float a0 = b1v.x, a1 = b1v.y, a2 = b1v.z, a3 = b1v.w;
      #pragma unroll
      for (int k = 0; k < 8; ++k) {
        float ev = __half2float(efv.hh[k]);
        const float4 w = *(const float4*)(W1 + k*64 + j1);
        a0 += ev*w.x; a1 += ev*w.y; a2 += ev*w.z; a3 += ev*w.w;
      }
      f16x4 pk;
      pk[0] = (_Float16)siluf(a0);
      pk[1] = (_Float16)siluf(a1);
      pk[2] = (_Float16)siluf(a2);
      pk[3] = (_Float16)siluf(a3);
      *(f16x4*)&hm1[ln15*72 + j1] = pk;
    }
    __syncthreads();   // B1: hm1 complete

    // ---- GEMM2: hm1(64) -> hm2(64), MFMA; wave owns cols wv*16..+15
    {
      f16x8 a20 = *(const f16x8*)(hm1 + ln15*72 + quad*8);
      f16x8 a21 = *(const f16x8*)(hm1 + ln15*72 + 32 + quad*8);
      int col = wv*16 + ln15;
      f32x4 d = {0.f, 0.f, 0.f, 0.f};
      d = __builtin_amdgcn_mfma_f32_16x16x32_f16(a20, *(const f16x8*)(W2t + (size_t)col*64 + quad*8), d, 0, 0, 0);
      d = __builtin_amdgcn_mfma_f32_16x16x32_f16(a21, *(const f16x8*)(W2t + (size_t)col*64 + 32 + quad*8), d, 0, 0, 0);
      #pragma unroll
      for (int r = 0; r < 4; ++r)
        hm2[(quad*4 + r)*72 + col] = (_Float16)siluf(d[r] + b2v);
    }
    __syncthreads();   // B2: hm2 complete

    // ---- GEMM3: hm2(64) -> this wave's 64 rw cols (wave-local), fp16 slab
    {
      f16x8 a30 = *(const f16x8*)(hm2 + ln15*72 + quad*8);
      f16x8 a31 = *(const f16x8*)(hm2 + ln15*72 + 32 + quad*8);
      #pragma unroll
      for (int cg = 0; cg < 4; ++cg) {
        int colg = (cg < 2) ? (wv*32 + cg*16 + ln15)
                            : (128 + wv*32 + (cg-2)*16 + ln15);
        f32x4 d = {0.f, 0.f, 0.f, 0.f};
        d = __builtin_amdgcn_mfma_f32_16x16x32_f16(a30, *(const f16x8*)(W3t + (size_t)colg*64 + quad*8), d, 0, 0, 0);
        d = __builtin_amdgcn_mfma_f32_16x16x32_f16(a31, *(const f16x8*)(W3t + (size_t)colg*64 + 32 + quad*8), d, 0, 0, 0);
        #pragma unroll
        for (int r = 0; r < 4; ++r)
          rww[(quad*4 + r)*68 + cg*16 + ln15] = (_Float16)d[r];
      }
    }

    // ---- prefetch next tile's elist + ef (overlaps with message loop)
    int2 eln_nxt = eln_cur; uint4 efq_nxt = efq_cur;
    if (base + 16 < deg) {
      int idx = base + 16 + lane;
      int cidx = idx < deg ? idx : deg - 1;
      if (lane < 16) eln_nxt = elist[beg + cidx];
      int e1 = __shfl(eln_nxt.x, ln15);
      efq_nxt = *(const uint4*)(ef + (size_t)e1*8);
    }

    // ---- message accumulate (wave-local rw reads, no barrier)
    #pragma unroll 4
    for (int i = 0; i < cnt; ++i) {
      int2 ed = elw[i];
      const float* hup = hu_in + (size_t)ed.y*512 + c*16;
      float  hj0 = hup[0];
      float2 hjm = *(const float2*)(hup + m0);
      float2 Ym  = *(const float2*)(Y + (size_t)ed.x*16 + m0);
      float w00 = (float)rww[i*68 + cl4 + l0];
      float w01 = (float)rww[i*68 + cl4 + l1];
      float w10 = (float)rww[i*68 + 32 + cl4 + l0];
      float w11 = (float)rww[i*68 + 32 + cl4 + l1];
      acc0 += w00 * Ym.x * hj0 + w10 * hjm.x;
      acc1 += w01 * Ym.y * hj0 + w11 * hjm.y;
    }

    eln_cur = eln_nxt; efq_cur = efq_nxt;
  }

  __syncthreads();   // all waves done with hm1/hm2/rw -> phase2 overlay safe

  // ---- agg + h into phase2 LDS
  al_s[c*16 + m0]     = acc0 * INV_AVG;
  al_s[c*16 + m0 + 1] = acc1 * INV_AVG;
  h2_s[t]       = hreg0;
  h2_s[t + 256] = hreg1;
  __syncthreads();

  // ---- update epilogue (coalesced weights, wave-uniform l)
  // out overlays h2_s column-by-column; hu overlays al_s column-by-column.
  int sp = species[n];
  float xn = xnode[n];
  int d = lane & 31, ch = lane >> 5;
  #pragma unroll
  for (int mi = 0; mi < 4; ++mi) {
    int m = wv*4 + mi;
    int l = lof(m);
    const float* wd  = Wd  + l*1024 + d;
    const float* wsc = Wsc + l*4096 + sp*32 + d;
    float a = 0.0f, s = 0.0f;
    #pragma unroll 4
    for (int cc = 0; cc < 16; ++cc) {
      int c2 = cc + ch*16;
      a += al_s[c2*16 + m] * wd[c2*32];
      s += h2_s[c2*16 + m] * wsc[c2*128];
    }
    a += __shfl_xor(a, 32);
    s += __shfl_xor(s, 32);
    float hn = a*xn + s;
    if (ch == 0) h2_s[d*16 + m] = hn;       // out (overlay, wave-exclusive col)
    if (has_next) {
      const float* wu = Wu_next + l*1024 + d;
      float u = 0.0f;
      #pragma unroll 4
      for (int cc = 0; cc < 16; ++cc) {
        int c2 = cc + ch*16;
        u += h2_s[c2*16 + m] * wu[c2*32];   // reads out (same wave wrote it)
      }
      u += __shfl_xor(u, 32);
      if (ch == 0) al_s[d*16 + m] = u;      // hu (overlay, wave-exclusive col)
    }
  }

  // readout (wave 0 reads its own out m=0 column)
  if (t < 64) {
    float pre = br1[t];
    #pragma unroll 4
    for (int cc = 0; cc < CC; ++cc) pre += h2_s[cc*16] * Wr1[cc*64 + t];
    float v = siluf(pre) * Wr2[t];
    #pragma unroll
    for (int off2 = 32; off2 > 0; off2 >>= 1) v += __shfl_down(v, off2);
    if (t == 0) node_e[n] += siluf(v);
  }
  __syncthreads();   // out/hu complete

  h[(size_t)n*512 + t]       = h2_s[t];
  h[(size_t)n*512 + t + 256] = h2_s[t + 256];
  if (has_next) {
    hu_out[(size_t)n*512 + t]       = al_s[t];
    hu_out[(size_t)n*512 + t + 256] = al_s[t + 256];
  }
}

// ---------------------------------------------------------------------------
// Kernel 7: per-graph sum of node energies
// ---------------------------------------------------------------------------
__global__ __launch_bounds__(128) void k_out(
    const float* __restrict__ node_e, float* __restrict__ out)
{
  int g = blockIdx.x, t = threadIdx.x;
  float v = (t < NPG) ? node_e[g*NPG + t] : 0.0f;
  #pragma unroll
  for (int off2 = 32; off2 > 0; off2 >>= 1) v += __shfl_down(v, off2);
  __shared__ float r2[2];
  if ((t & 63) == 0) r2[t >> 6] = v;
  __syncthreads();
  if (t == 0) out[g] = r2[0] + r2[1];
}

// Diagnostic: if workspace too small, report its size (MB) via absmax
__global__ void k_dbg(float* __restrict__ out, float v) {
  int i = blockIdx.x * 64 + threadIdx.x;
  if (i < GG) out[i] = v;
}

// ---------------------------------------------------------------------------
extern "C" void kernel_launch(void* const* d_in, const int* in_sizes, int n_in,
                              void* d_out, int out_size, void* d_ws, size_t ws_size,
                              hipStream_t stream)
{
  const float* positions = (const float*)d_in[0];
  const float* cell      = (const float*)d_in[1];
  const int*   Sij       = (const int*)d_in[2];
  const int*   eidx      = (const int*)d_in[3];
  const int*   species   = (const int*)d_in[4];
  const int*   batch     = (const int*)d_in[5];
  const float* W_emb     = (const float*)d_in[6];
  const float* W_xtp     = (const float*)d_in[7];
  const float* W_up      = (const float*)d_in[8];
  const float* W1        = (const float*)d_in[9];
  const float* b1        = (const float*)d_in[10];
  const float* W2        = (const float*)d_in[11];
  const float* b2        = (const float*)d_in[12];
  const float* W3        = (const float*)d_in[13];
  const float* W_down    = (const float*)d_in[14];
  const float* W_sc      = (const float*)d_in[15];
  const float* Wr1       = (const float*)d_in[16];
  const float* br1       = (const float*)d_in[17];
  const float* Wr2       = (const float*)d_in[18];
  float* out = (float*)d_out;
  (void)in_sizes; (void)n_in; (void)out_size;

  const size_t NEED = 100000000;
  if (ws_size < NEED) {
    k_dbg<<<dim3(2), dim3(64), 0, stream>>>(out, (float)(ws_size >> 20));
    return;
  }

  char* ws = (char*)d_ws;
  size_t off = 0;
  auto alloc = [&](size_t bytes) -> void* {
    void* p = ws + off;
    off += (bytes + 255) & ~(size_t)255;
    return p;
  };
  float*     Yb      = (float*)alloc((size_t)EE*16*4);   // 25.6 MB
  __half*    efb     = (__half*)alloc((size_t)EE*8*2);   //  6.4 MB
  float*     hb      = (float*)alloc((size_t)NN*512*4);  // 20.5 MB
  float*     huA     = (float*)alloc((size_t)NN*512*4);  // 20.5 MB
  float*     huB     = (float*)alloc((size_t)NN*512*4);  // 20.5 MB
  float*     xnodeb  = (float*)alloc((size_t)NN*4);
  float*     node_eb = (float*)alloc((size_t)NN*4);
  int*       offb    = (int*)alloc((size_t)(NN+1)*4);
  int*       curb    = (int*)alloc((size_t)NN*4);
  int2*      elistb  = (int2*)alloc((size_t)EE*8);       //  3.2 MB
  _Float16*  W2tb    = (_Float16*)alloc((size_t)NLAYER*64*64*2);
  _Float16*  W3tb    = (_Float16*)alloc((size_t)NLAYER*64*256*2);

  dim3 blk(256);
  k_geom<<<dim3((EE + 255)/256), blk, 0, stream>>>(positions, cell, Sij, eidx, batch, Yb, efb);
  k_init<<<dim3((NN*CC + 255)/256), blk, 0, stream>>>(species, W_emb, W_xtp, hb, xnodeb, node_eb);
  k_wconv<<<dim3((NLAYER*64*256 + 255)/256), blk, 0, stream>>>(W2, W3, W2tb, W3tb);

  // CSR build (layer-invariant)
  k_csr_zero <<<dim3((NN + 255)/256), blk, 0, stream>>>(curb);
  k_csr_count<<<dim3((EE + 255)/256), blk, 0, stream>>>(eidx, curb);
  k_csr_scan <<<dim3(GG), dim3(128), 0, stream>>>(curb, offb, curb);
  k_csr_fill <<<dim3((EE + 255)/256), blk, 0, stream>>>(eidx, curb, elistb);

  // layer 0 hu from initial h
  k_hu<<<dim3(NN), blk, 0, stream>>>(hb, W_up + 0*4096, huA);

  float* hin = huA; float* hout = huB;
  for (int layer = 0; layer < NLAYER; ++layer) {
    int has_next = (layer + 1 < NLAYER) ? 1 : 0;
    k_gather<<<dim3(NN), blk, 0, stream>>>(elistb, offb, Yb, efb,
        W1 + layer*NBES*64, b1 + layer*64,
        W2tb + layer*4096, b2 + layer*64,
        W3tb + layer*16384, hin,
        species, xnodeb,
        W_down + layer*4096, W_sc + layer*16384,
        Wr1 + layer*CC*64, br1 + layer*64, Wr2 + layer*64, node_eb,
        W_up + (has_next ? (layer+1)*4096 : 0), hout, hb, has_next);
    float* tmp = hin; hin = hout; hout = tmp;
  }
  k_out<<<dim3(GG), dim3(128), 0, stream>>>(node_eb, out);
}